// Round 19
// baseline (65.054 us; speedup 1.0000x reference)
//
#include <hip/hip_runtime.h>
#include <math.h>

#define NPX 1024  // H*W = 32*32

using bf16x8 = __attribute__((ext_vector_type(8))) short;  // 8 bf16 in 4 VGPRs
using f32x4  = __attribute__((ext_vector_type(4))) float;
using u32x4  = __attribute__((ext_vector_type(4))) unsigned;

__device__ __forceinline__ float fast_slog1p(float p) {
  // ln(1+|p|) via v_log_f32; 1+|p| in [1,~3] so no catastrophic cancellation
  return copysignf(__logf(1.f + fabsf(p)), p);
}

__device__ __forceinline__ unsigned short f2bf(float f) {
  unsigned u = __builtin_bit_cast(unsigned, f);
  unsigned r = (u + 0x7FFFu + ((u >> 16) & 1u)) >> 16;  // RNE
  return (unsigned short)r;
}
__device__ __forceinline__ float bf2f(unsigned short h) {
  return __builtin_bit_cast(float, (unsigned)h << 16);
}
// HW packed conversion: low16 = bf16(lo), high16 = bf16(hi)
__device__ __forceinline__ unsigned cvt_pk(float lo, float hi) {
  unsigned r;
  asm("v_cvt_pk_bf16_f32 %0, %1, %2" : "=v"(r) : "v"(lo), "v"(hi));
  return r;
}

// ---------------------------------------------------------------------------
// K1: FUSED front-end. Blocks 0..511: grouped 1x1 conv q = x*q_w (+ qT).
// Blocks 512..1023: pack out_w -> whP/wlP. Block 1024: pack cpb_w2 -> w2P.
// ---------------------------------------------------------------------------
__global__ __launch_bounds__(256) void k_pre(
    const float* __restrict__ x, const float* __restrict__ qw,
    const float* __restrict__ ow, const float* __restrict__ w2g,
    float* __restrict__ q, float* __restrict__ qT,
    unsigned short* __restrict__ whP, unsigned short* __restrict__ wlP,
    unsigned short* __restrict__ w2P) {
  const int blk = blockIdx.x;
  const int tid = threadIdx.x;
  if (blk < 512) {
    // ---- qconv: 16 bg x 16 px-tiles of 32 ----
    const int bg  = blk >> 5;
    const int px0 = (blk & 31) << 5;
    const int g   = bg & 7;
    const int b   = bg >> 3;
    __shared__ float xs[32 * 32];      // [c][p]
    __shared__ float wsh[64 * 32];     // [o][c]
    __shared__ float ot[64 * 33];      // transpose staging, padded

    const float* xb = x + ((size_t)(b * 256 + g * 32)) * NPX + px0;
    for (int idx = tid; idx < 32 * 32; idx += 256) {
      int c = idx >> 5, p = idx & 31;
      xs[idx] = xb[(size_t)c * NPX + p];
    }
    const float* wb = qw + g * 64 * 32;
    for (int idx = tid; idx < 64 * 32; idx += 256) wsh[idx] = wb[idx];
    __syncthreads();

    for (int idx = tid; idx < 64 * 32; idx += 256) {
      int o = idx >> 5, p = idx & 31;
      float a0 = 0.f, a1 = 0.f;
#pragma unroll
      for (int c = 0; c < 32; c += 2) {
        a0 = fmaf(wsh[o * 32 + c],     xs[c * 32 + p],       a0);
        a1 = fmaf(wsh[o * 32 + c + 1], xs[(c + 1) * 32 + p], a1);
      }
      float acc = a0 + a1;
      q[((size_t)(bg * 64 + o)) * NPX + px0 + p] = acc;
      ot[o * 33 + p] = acc * 0.125f;
    }
    __syncthreads();
    float* qTb = qT + ((size_t)bg * NPX + px0) * 64;
    for (int idx = tid; idx < 32 * 64; idx += 256) {
      int p = idx >> 6, o = idx & 63;
      qTb[p * 64 + o] = ot[o * 33 + p];
    }
  } else if (blk < 1024) {
    // ---- out_w -> whP/wlP (fragment-major bf16 hi/lo) ----
    int idx = (blk - 512) * 256 + tid;  // 0..131071
    int o = idx >> 9, c = idx & 511;
    float v = ow[(size_t)o * 512 + c];
    unsigned short hi = f2bf(v);
    unsigned short lo = f2bf(v - bf2f(hi));
    int kt = c >> 5, lg = (c >> 3) & 3, r = c & 7;
    size_t dst = ((size_t)(kt * 4 + lg) * 256 + o) * 8 + r;
    whP[dst] = hi;
    wlP[dst] = lo;
  } else {
    // ---- cpb_w2 -> w2P (fragment-major bf16) ----
    for (int e = tid; e < 4096; e += 256) {
      int r = e & 7;
      int f = (e >> 3) & 7;        // c2t*2+s
      int c2t = f >> 1, s = f & 1;
      int lane = e >> 6;           // lg*16+lm
      int lm = lane & 15, lg = lane >> 4;
      int c2 = c2t * 16 + lm, c = s * 32 + lg * 8 + r;
      w2P[e] = f2bf(w2g[c2 * 64 + c]);
    }
  }
}

// ---------------------------------------------------------------------------
// K2+K3: offset net + grid_sample + k/v convs, partitioned over px.
// grid: (8 px-chunks of 8, 16 bg), 512 thr (8 waves).
// ---------------------------------------------------------------------------
__global__ __launch_bounds__(512) void k_offset_sample(
    const float* __restrict__ q, const float* __restrict__ w1,
    const float* __restrict__ b1, const float* __restrict__ w2,
    const float* __restrict__ x, const float* __restrict__ kw,
    const float* __restrict__ vw, float* __restrict__ gkv,
    float* __restrict__ kh,
    unsigned short* __restrict__ vPh, unsigned short* __restrict__ vPl) {
  const int px0 = blockIdx.x << 3;   // 0,8,...,56
  const int bg  = blockIdx.y;
  const int g   = bg & 7;
  const int tid = threadIdx.x;
  __shared__ float ge[64 * 9];       // [c][lp] gelu outs, padded
  __shared__ float w1s[64 * 36];
  __shared__ float b1s[64];
  __shared__ float kws[64 * 33];
  __shared__ float vws[64 * 33];
  __shared__ float smp[32 * 9];      // [c][lj] sampled, padded
  __shared__ float xs_[8], ys_[8];

  for (int idx = tid; idx < 64 * 36; idx += 512) w1s[idx] = w1[idx];
  if (tid < 64) b1s[tid] = b1[tid];
  for (int idx = tid; idx < 2048; idx += 512) {
    int o = idx >> 5, c = idx & 31;
    kws[o * 33 + c] = kw[(g * 64 + o) * 32 + c];
    vws[o * 33 + c] = vw[(g * 64 + o) * 32 + c];
  }
  __syncthreads();

  // depthwise 6x6 s4 + bias + exact GELU: 64 c x 8 px, 1 per thread
  const float* qb = q + (size_t)bg * 64 * NPX;
  {
    int idx = tid;  // 0..511
    int c = idx >> 3, lp = idx & 7;
    int px = px0 + lp;
    int oy = px >> 3, ox = px & 7;
    const float* qc = qb + (size_t)c * NPX;
    float acc = 0.f;
#pragma unroll
    for (int ky = 0; ky < 6; ++ky) {
      int yy = oy * 4 - 1 + ky;
      if (yy < 0 || yy >= 32) continue;
#pragma unroll
      for (int kx = 0; kx < 6; ++kx) {
        int xx = ox * 4 - 1 + kx;
        if (xx < 0 || xx >= 32) continue;
        acc = fmaf(w1s[c * 36 + ky * 6 + kx], qc[yy * 32 + xx], acc);
      }
    }
    acc += b1s[c];
    ge[c * 9 + lp] = 0.5f * acc * (1.f + erff(acc * 0.70710678118654752440f));
  }
  __syncthreads();

  // 1x1 (64->2): 64 lanes per px, 1 channel each, shfl-reduce width 64
  {
    int lp = tid >> 6, sl = tid & 63;
    float gv = ge[sl * 9 + lp];
    float s0 = w2[sl] * gv;
    float s1 = w2[64 + sl] * gv;
#pragma unroll
    for (int off = 32; off > 0; off >>= 1) {
      s0 += __shfl_xor(s0, off, 64);
      s1 += __shfl_xor(s1, off, 64);
    }
    if (sl == 0) {
      float o0 = tanhf(s0) * 4.f;
      float o1 = tanhf(s1) * 4.f;
      int px = px0 + lp;
      int oy = px >> 3, ox = px & 7;
      float g0 = 2.f * ((float)ox + o0) / 7.f - 1.f;
      float g1 = 2.f * ((float)oy + o1) / 7.f - 1.f;
      gkv[(bg * 64 + px) * 2 + 0] = g0;
      gkv[(bg * 64 + px) * 2 + 1] = g1;
      xs_[lp] = (g0 + 1.f) * 16.f - 0.5f;
      ys_[lp] = (g1 + 1.f) * 16.f - 0.5f;
    }
  }
  __syncthreads();

  // bilinear sample: 32 c x 8 j (only tid<256 active)
  const float* imgb = x + (size_t)bg * 32 * NPX;
  if (tid < 256) {
    int c = tid >> 3, lj = tid & 7;
    float xx = xs_[lj], yy = ys_[lj];
    float x0f = floorf(xx), y0f = floorf(yy);
    int x0 = (int)x0f, y0 = (int)y0f;
    float wx1 = xx - x0f, wy1 = yy - y0f;
    float wx0 = 1.f - wx1, wy0 = 1.f - wy1;
    int x1 = x0 + 1, y1 = y0 + 1;
    bool vx0 = (x0 >= 0) & (x0 < 32), vx1 = (x1 >= 0) & (x1 < 32);
    bool vy0 = (y0 >= 0) & (y0 < 32), vy1 = (y1 >= 0) & (y1 < 32);
    int cx0 = min(max(x0, 0), 31), cx1 = min(max(x1, 0), 31);
    int cy0 = min(max(y0, 0), 31), cy1 = min(max(y1, 0), 31);
    const float* img = imgb + (size_t)c * NPX;
    float v00 = (vy0 && vx0) ? img[cy0 * 32 + cx0] : 0.f;
    float v01 = (vy0 && vx1) ? img[cy0 * 32 + cx1] : 0.f;
    float v10 = (vy1 && vx0) ? img[cy1 * 32 + cx0] : 0.f;
    float v11 = (vy1 && vx1) ? img[cy1 * 32 + cx1] : 0.f;
    smp[c * 9 + lj] = v00 * wy0 * wx0 + v01 * wy0 * wx1 +
                      v10 * wy1 * wx0 + v11 * wy1 * wx1;
  }
  __syncthreads();

  // k/v 1x1 convs: 8 j x 64 o, 1 per thread
  {
    int lj = tid >> 6, o = tid & 63;
    int j = px0 + lj;
    float ak0 = 0.f, ak1 = 0.f, av0 = 0.f, av1 = 0.f;
#pragma unroll
    for (int c = 0; c < 32; c += 2) {
      float s0 = smp[c * 9 + lj], s1 = smp[(c + 1) * 9 + lj];
      ak0 = fmaf(kws[o * 33 + c],     s0, ak0);
      ak1 = fmaf(kws[o * 33 + c + 1], s1, ak1);
      av0 = fmaf(vws[o * 33 + c],     s0, av0);
      av1 = fmaf(vws[o * 33 + c + 1], s1, av1);
    }
    kh[((size_t)bg * 64 + j) * 64 + o] = ak0 + ak1;
    // V -> bf16 hi/lo in MFMA B-fragment layout:
    float av = av0 + av1;
    unsigned short hi = f2bf(av);
    unsigned short lo = f2bf(av - bf2f(hi));
    int s  = (j >> 5) & 1, lgj = (j >> 3) & 3, r = j & 7;
    int nb = o >> 4, lmo = o & 15;
    size_t dst = (((size_t)(bg * 4 + nb) * 64) + lgj * 16 + lmo) * 16 + s * 8 + r;
    vPh[dst] = hi;
    vPl[dst] = lo;
  }
}

// ---------------------------------------------------------------------------
// K4: fused CPB-MLP + QK^T + softmax + PV, all MFMA (round-15 form + K-load
// hoist: kh loads issued in prologue so their latency drains under CPB).
// Only LDS is sim (4.2 KB); 2 barriers total.
// grid: (64 tiles, 16 bh), 256 thr = 4 waves; wave w owns j-cols [16w,16w+16)
// ---------------------------------------------------------------------------
__global__ __launch_bounds__(256) void k_attn(
    const float* __restrict__ qT, const float* __restrict__ kh,
    const unsigned short* __restrict__ vPh, const unsigned short* __restrict__ vPl,
    const float* __restrict__ gkv,
    const float* __restrict__ w1, const float* __restrict__ b1,
    const unsigned short* __restrict__ w2P, const float* __restrict__ b2,
    const float* __restrict__ w3, const float* __restrict__ b3,
    unsigned short* __restrict__ aoh, unsigned short* __restrict__ aol) {
  const int it  = blockIdx.x;     // 0..63
  const int bh  = blockIdx.y;     // 0..15
  const int i0  = it << 4;
  const int iy  = i0 >> 5;
  const int ixb = i0 & 31;
  const int tid = threadIdx.x;

  __shared__ float sim[16 * 65];

  const int w  = tid >> 6;   // wave 0..3
  const int l  = tid & 63;
  const int lm = l & 15;
  const int lg = l >> 4;
  const int jb = w * 16;
  const int j  = jb + lm;    // this thread's j-column for CPB/QK

  // --- W2 fragments: 8x coalesced 16B loads from packed global ---
  bf16x8 bw2[4][2];
  {
    const unsigned short* wp = w2P + (lg * 16 + lm) * 64;
#pragma unroll
    for (int c2t = 0; c2t < 4; ++c2t)
#pragma unroll
      for (int s = 0; s < 2; ++s)
        bw2[c2t][s] = *(const bf16x8*)(wp + (c2t * 2 + s) * 8);
  }
  // --- V B-fragments: 4 coalesced 16B loads from packed global ---
  bf16x8 bvh[2], bvl[2];
  {
    const size_t vbase = (((size_t)(bh * 4 + w) * 64) + l) * 16;
#pragma unroll
    for (int s = 0; s < 2; ++s) {
      bvh[s] = *(const bf16x8*)(vPh + vbase + s * 8);
      bvl[s] = *(const bf16x8*)(vPl + vbase + s * 8);
    }
  }
  // --- K-operand loads issued EARLY (latency hides under CPB) ---
  float4 k0e[2], k1e[2];
  {
    const float* kb = kh + ((size_t)(bh * 64 + j)) * 64;
#pragma unroll
    for (int s = 0; s < 2; ++s) {
      k0e[s] = *(const float4*)(kb + s * 32 + lg * 8);
      k1e[s] = *(const float4*)(kb + s * 32 + lg * 8 + 4);
    }
  }

  // --- per-thread scalars (no LDS): k-grid coords + layer-1 hoists ---
  float kxv, vvj;
  {
    float2 kg = *(const float2*)(gkv + (bh * 64 + j) * 2);
    kxv = kg.x;
    float qyn = (2.f / 31.f) * (float)iy - 1.f;
    vvj = fast_slog1p(qyn - kg.y);
  }
  float w1v[16], tc[16];
#pragma unroll
  for (int s = 0; s < 2; ++s)
#pragma unroll
    for (int r = 0; r < 8; ++r) {
      int c = s * 32 + lg * 8 + r;
      float2 wv = *(const float2*)(w1 + c * 2);   // (w1x, w1y)
      w1v[s * 8 + r] = wv.x;
      tc[s * 8 + r]  = fmaf(wv.y, vvj, b1[c]);
    }
  // per-lane layer-3 constants: c2 = c2t*16 + lg*4 + r
  float b2r[4][4], w3r[4][4];
#pragma unroll
  for (int c2t = 0; c2t < 4; ++c2t)
#pragma unroll
    for (int r = 0; r < 4; ++r) {
      int c2 = c2t * 16 + lg * 4 + r;
      b2r[c2t][r] = b2[c2];
      w3r[c2t][r] = w3[c2];
    }
  const float b3v = b3[0];
  const float qxn0 = (2.f / 31.f) * (float)ixb - 1.f;

  // --- CPB pass: swapped operands; lane lm = point j-within-16; unroll 2 ---
#pragma unroll 2
  for (int il = 0; il < 16; ++il) {
    float qxn = fmaf((float)il, 2.f / 31.f, qxn0);
    float u = fast_slog1p(qxn - kxv);
    float h[16];
#pragma unroll
    for (int e = 0; e < 16; ++e)
      h[e] = fmaxf(fmaf(w1v[e], u, tc[e]), 0.f);
    bf16x8 hf[2];   // B-fragment: col=point=lm, k=c
#pragma unroll
    for (int s = 0; s < 2; ++s) {
      u32x4 wds;
#pragma unroll
      for (int p = 0; p < 4; ++p)
        wds[p] = cvt_pk(h[s * 8 + p * 2], h[s * 8 + p * 2 + 1]);
      hf[s] = __builtin_bit_cast(bf16x8, wds);
    }
    // D[m=c2][n=point]: lane holds point=lm, c2 = c2t*16 + lg*4 + r
    float tot = 0.f;
#pragma unroll
    for (int c2t = 0; c2t < 4; ++c2t) {
      f32x4 acc = (f32x4){b2r[c2t][0], b2r[c2t][1], b2r[c2t][2], b2r[c2t][3]};
      acc = __builtin_amdgcn_mfma_f32_16x16x32_bf16(bw2[c2t][0], hf[0], acc, 0, 0, 0);
      acc = __builtin_amdgcn_mfma_f32_16x16x32_bf16(bw2[c2t][1], hf[1], acc, 0, 0, 0);
#pragma unroll
      for (int r = 0; r < 4; ++r)
        tot = fmaf(fmaxf(acc[r], 0.f), w3r[c2t][r], tot);
    }
    tot += __shfl_xor(tot, 16);
    tot += __shfl_xor(tot, 32);
    if (lg == 0)
      sim[il * 65 + jb + lm] = tot + b3v;
  }

  // --- QK pass: q loads late, k loads already in flight/registers ---
  {
    bf16x8 aq[2], bk[2];
    const float* qb = qT + ((size_t)bh * NPX + i0 + lm) * 64;
#pragma unroll
    for (int s = 0; s < 2; ++s) {
      float4 q0 = *(const float4*)(qb + s * 32 + lg * 8);
      float4 q1 = *(const float4*)(qb + s * 32 + lg * 8 + 4);
      u32x4 wq, wk;
      wq[0] = cvt_pk(q0.x, q0.y); wq[1] = cvt_pk(q0.z, q0.w);
      wq[2] = cvt_pk(q1.x, q1.y); wq[3] = cvt_pk(q1.z, q1.w);
      wk[0] = cvt_pk(k0e[s].x, k0e[s].y); wk[1] = cvt_pk(k0e[s].z, k0e[s].w);
      wk[2] = cvt_pk(k1e[s].x, k1e[s].y); wk[3] = cvt_pk(k1e[s].z, k1e[s].w);
      aq[s] = __builtin_bit_cast(bf16x8, wq);
      bk[s] = __builtin_bit_cast(bf16x8, wk);
    }
    f32x4 qacc = (f32x4){0.f, 0.f, 0.f, 0.f};
    qacc = __builtin_amdgcn_mfma_f32_16x16x32_bf16(aq[0], bk[0], qacc, 0, 0, 0);
    qacc = __builtin_amdgcn_mfma_f32_16x16x32_bf16(aq[1], bk[1], qacc, 0, 0, 0);
#pragma unroll
    for (int r = 0; r < 4; ++r)
      sim[(lg * 4 + r) * 65 + jb + lm] += qacc[r];
  }
  __syncthreads();

  // --- softmax: 16 threads per row of 64 (fast exp) ---
  {
    int r = tid >> 4, sl = tid & 15;
    float sv[4];
    float m = -1e30f;
#pragma unroll
    for (int t = 0; t < 4; ++t) {
      sv[t] = sim[r * 65 + sl + (t << 4)];
      m = fmaxf(m, sv[t]);
    }
#pragma unroll
    for (int off = 8; off > 0; off >>= 1) m = fmaxf(m, __shfl_xor(m, off, 16));
    float ssum = 0.f;
#pragma unroll
    for (int t = 0; t < 4; ++t) { sv[t] = __expf(sv[t] - m); ssum += sv[t]; }
#pragma unroll
    for (int off = 8; off > 0; off >>= 1) ssum += __shfl_xor(ssum, off, 16);
    float inv = 1.f / ssum;
#pragma unroll
    for (int t = 0; t < 4; ++t) sim[r * 65 + sl + (t << 4)] = sv[t] * inv;
  }
  __syncthreads();

  // --- PV via MFMA (P bf16 x V hi/lo), direct hi/lo epilogue ---
  {
    bf16x8 ap[2];
#pragma unroll
    for (int s = 0; s < 2; ++s) {
      u32x4 wp;
#pragma unroll
      for (int p = 0; p < 4; ++p)
        wp[p] = cvt_pk(sim[lm * 65 + s * 32 + lg * 8 + p * 2],
                       sim[lm * 65 + s * 32 + lg * 8 + p * 2 + 1]);
      ap[s] = __builtin_bit_cast(bf16x8, wp);
    }
    f32x4 po = (f32x4){0.f, 0.f, 0.f, 0.f};
    po = __builtin_amdgcn_mfma_f32_16x16x32_bf16(ap[0], bvh[0], po, 0, 0, 0);
    po = __builtin_amdgcn_mfma_f32_16x16x32_bf16(ap[1], bvh[1], po, 0, 0, 0);
    po = __builtin_amdgcn_mfma_f32_16x16x32_bf16(ap[0], bvl[0], po, 0, 0, 0);
    po = __builtin_amdgcn_mfma_f32_16x16x32_bf16(ap[1], bvl[1], po, 0, 0, 0);
    const int b = bh >> 3, h = bh & 7;
    size_t base = ((size_t)(b * 1024 + i0 + lg * 4)) * 512 + h * 64 + jb + lm;
#pragma unroll
    for (int r = 0; r < 4; ++r) {
      float v = po[r];
      unsigned short hi = f2bf(v);
      aoh[base + (size_t)r * 512] = hi;
      aol[base + (size_t)r * 512] = f2bf(v - bf2f(hi));
    }
  }
}

// ---------------------------------------------------------------------------
// K5: projection as split-bf16 MFMA GEMM. No barriers -> 1 wave per block;
// 512 blocks (128 px-tiles x 4 o-quarters) spread across all 256 CUs.
// ---------------------------------------------------------------------------
__global__ __launch_bounds__(64) void k_proj_mfma(
    const unsigned short* __restrict__ aoh, const unsigned short* __restrict__ aol,
    const unsigned short* __restrict__ whP, const unsigned short* __restrict__ wlP,
    const float* __restrict__ ob, float* __restrict__ out) {
  const int blkid = blockIdx.x;      // 0..511
  const int pt  = blkid >> 2;        // px tile 0..127
  const int oq  = blkid & 3;         // o-quarter
  const int p0  = pt << 4;
  const int b   = p0 >> 10;
  const int pb  = p0 & 1023;
  const int l   = threadIdx.x;       // 0..63
  const int lm  = l & 15, lg = l >> 4;
  const int ob0 = oq * 64;

  f32x4 acc[4];
#pragma unroll
  for (int nt = 0; nt < 4; ++nt) acc[nt] = (f32x4){0.f, 0.f, 0.f, 0.f};

  const unsigned short* arh = aoh + ((size_t)(p0 + lm)) * 512 + lg * 8;
  const unsigned short* arl = aol + ((size_t)(p0 + lm)) * 512 + lg * 8;

#pragma unroll 4
  for (int kt = 0; kt < 16; ++kt) {
    bf16x8 ah = *(const bf16x8*)(arh + kt * 32);
    bf16x8 al = *(const bf16x8*)(arl + kt * 32);
    const size_t wb = ((size_t)(kt * 4 + lg) * 256 + ob0 + lm) * 8;
#pragma unroll
    for (int nt = 0; nt < 4; ++nt) {
      bf16x8 bhf = *(const bf16x8*)(whP + wb + nt * 128);
      bf16x8 blf = *(const bf16x8*)(wlP + wb + nt * 128);
      acc[nt] = __builtin_amdgcn_mfma_f32_16x16x32_bf16(ah, bhf, acc[nt], 0, 0, 0);
      acc[nt] = __builtin_amdgcn_mfma_f32_16x16x32_bf16(ah, blf, acc[nt], 0, 0, 0);
      acc[nt] = __builtin_amdgcn_mfma_f32_16x16x32_bf16(al, bhf, acc[nt], 0, 0, 0);
    }
  }
#pragma unroll
  for (int nt = 0; nt < 4; ++nt) {
    int o = ob0 + nt * 16 + lm;
    float bias = ob[o];
    float4 v;
    v.x = acc[nt][0] + bias;
    v.y = acc[nt][1] + bias;
    v.z = acc[nt][2] + bias;
    v.w = acc[nt][3] + bias;
    *(float4*)(out + ((size_t)(b * 256 + o)) * NPX + pb + lg * 4) = v;
  }
}

// ---------------------------------------------------------------------------
extern "C" void kernel_launch(void* const* d_in, const int* in_sizes, int n_in,
                              void* d_out, int out_size, void* d_ws, size_t ws_size,
                              hipStream_t stream) {
  const float* x      = (const float*)d_in[0];
  const float* q_w    = (const float*)d_in[1];
  const float* k_w    = (const float*)d_in[2];
  const float* v_w    = (const float*)d_in[3];
  const float* out_w  = (const float*)d_in[4];
  const float* out_b  = (const float*)d_in[5];
  const float* off_w1 = (const float*)d_in[6];
  const float* off_b1 = (const float*)d_in[7];
  const float* off_w2 = (const float*)d_in[8];
  const float* cpb_w1 = (const float*)d_in[9];
  const float* cpb_b1 = (const float*)d_in[10];
  const float* cpb_w2 = (const float*)d_in[11];
  const float* cpb_b2 = (const float*)d_in[12];
  const float* cpb_w3 = (const float*)d_in[13];
  const float* cpb_b3 = (const float*)d_in[14];
  float* out = (float*)d_out;

  float* ws  = (float*)d_ws;
  float* q   = ws;                          // 1048576 f; reused as aoh/aol
  unsigned short* aoh = (unsigned short*)q; // 2048*512 shorts
  unsigned short* aol = aoh + 2048 * 512;   // 2048*512 shorts
  float* qT  = ws + 1048576;                // 1048576 f
  float* kh  = qT + 1048576;                // 65536 f
  float* gkv = kh + 65536;                  // 2048 f
  unsigned short* whP = (unsigned short*)(gkv + 2048);  // 131072 shorts
  unsigned short* wlP = whP + 131072;                   // 131072 shorts
  unsigned short* w2P = wlP + 131072;                   // 4096 shorts
  unsigned short* vPh = w2P + 4096;                     // 65536 shorts
  unsigned short* vPl = vPh + 65536;                    // 65536 shorts

  k_pre<<<1025, 256, 0, stream>>>(x, q_w, out_w, cpb_w2, q, qT, whP, wlP, w2P);
  k_offset_sample<<<dim3(8, 16), 512, 0, stream>>>(q, off_w1, off_b1, off_w2,
                                                   x, k_w, v_w, gkv, kh, vPh, vPl);
  k_attn<<<dim3(64, 16), 256, 0, stream>>>(qT, kh, vPh, vPl, gkv, cpb_w1, cpb_b1,
                                           w2P, cpb_b2, cpb_w3, cpb_b3,
                                           aoh, aol);
  k_proj_mfma<<<512, 64, 0, stream>>>(aoh, aol, whP, wlP, out_b, out);
}

// Round 20
// 62.762 us; speedup vs baseline: 1.0365x; 1.0365x over previous
//
#include <hip/hip_runtime.h>
#include <math.h>

#define NPX 1024  // H*W = 32*32

using bf16x8 = __attribute__((ext_vector_type(8))) short;  // 8 bf16 in 4 VGPRs
using f32x4  = __attribute__((ext_vector_type(4))) float;
using u32x4  = __attribute__((ext_vector_type(4))) unsigned;

__device__ __forceinline__ float fast_slog1p(float p) {
  // ln(1+|p|) via v_log_f32; 1+|p| in [1,~3] so no catastrophic cancellation
  return copysignf(__logf(1.f + fabsf(p)), p);
}

__device__ __forceinline__ unsigned short f2bf(float f) {
  unsigned u = __builtin_bit_cast(unsigned, f);
  unsigned r = (u + 0x7FFFu + ((u >> 16) & 1u)) >> 16;  // RNE
  return (unsigned short)r;
}
__device__ __forceinline__ float bf2f(unsigned short h) {
  return __builtin_bit_cast(float, (unsigned)h << 16);
}
// HW packed conversion: low16 = bf16(lo), high16 = bf16(hi)
__device__ __forceinline__ unsigned cvt_pk(float lo, float hi) {
  unsigned r;
  asm("v_cvt_pk_bf16_f32 %0, %1, %2" : "=v"(r) : "v"(lo), "v"(hi));
  return r;
}

// ---------------------------------------------------------------------------
// K1: FUSED front-end. Blocks 0..511: grouped 1x1 conv q = x*q_w (+ qT).
// Blocks 512..1023: pack out_w -> whP/wlP. Block 1024: pack cpb_w2 -> w2P.
// ---------------------------------------------------------------------------
__global__ __launch_bounds__(256) void k_pre(
    const float* __restrict__ x, const float* __restrict__ qw,
    const float* __restrict__ ow, const float* __restrict__ w2g,
    float* __restrict__ q, float* __restrict__ qT,
    unsigned short* __restrict__ whP, unsigned short* __restrict__ wlP,
    unsigned short* __restrict__ w2P) {
  const int blk = blockIdx.x;
  const int tid = threadIdx.x;
  if (blk < 512) {
    // ---- qconv: 16 bg x 16 px-tiles of 32 ----
    const int bg  = blk >> 5;
    const int px0 = (blk & 31) << 5;
    const int g   = bg & 7;
    const int b   = bg >> 3;
    __shared__ float xs[32 * 32];      // [c][p]
    __shared__ float wsh[64 * 32];     // [o][c]
    __shared__ float ot[64 * 33];      // transpose staging, padded

    const float* xb = x + ((size_t)(b * 256 + g * 32)) * NPX + px0;
    for (int idx = tid; idx < 32 * 32; idx += 256) {
      int c = idx >> 5, p = idx & 31;
      xs[idx] = xb[(size_t)c * NPX + p];
    }
    const float* wb = qw + g * 64 * 32;
    for (int idx = tid; idx < 64 * 32; idx += 256) wsh[idx] = wb[idx];
    __syncthreads();

    for (int idx = tid; idx < 64 * 32; idx += 256) {
      int o = idx >> 5, p = idx & 31;
      float a0 = 0.f, a1 = 0.f;
#pragma unroll
      for (int c = 0; c < 32; c += 2) {
        a0 = fmaf(wsh[o * 32 + c],     xs[c * 32 + p],       a0);
        a1 = fmaf(wsh[o * 32 + c + 1], xs[(c + 1) * 32 + p], a1);
      }
      float acc = a0 + a1;
      q[((size_t)(bg * 64 + o)) * NPX + px0 + p] = acc;
      ot[o * 33 + p] = acc * 0.125f;
    }
    __syncthreads();
    float* qTb = qT + ((size_t)bg * NPX + px0) * 64;
    for (int idx = tid; idx < 32 * 64; idx += 256) {
      int p = idx >> 6, o = idx & 63;
      qTb[p * 64 + o] = ot[o * 33 + p];
    }
  } else if (blk < 1024) {
    // ---- out_w -> whP/wlP (fragment-major bf16 hi/lo) ----
    int idx = (blk - 512) * 256 + tid;  // 0..131071
    int o = idx >> 9, c = idx & 511;
    float v = ow[(size_t)o * 512 + c];
    unsigned short hi = f2bf(v);
    unsigned short lo = f2bf(v - bf2f(hi));
    int kt = c >> 5, lg = (c >> 3) & 3, r = c & 7;
    size_t dst = ((size_t)(kt * 4 + lg) * 256 + o) * 8 + r;
    whP[dst] = hi;
    wlP[dst] = lo;
  } else {
    // ---- cpb_w2 -> w2P (fragment-major bf16) ----
    for (int e = tid; e < 4096; e += 256) {
      int r = e & 7;
      int f = (e >> 3) & 7;        // c2t*2+s
      int c2t = f >> 1, s = f & 1;
      int lane = e >> 6;           // lg*16+lm
      int lm = lane & 15, lg = lane >> 4;
      int c2 = c2t * 16 + lm, c = s * 32 + lg * 8 + r;
      w2P[e] = f2bf(w2g[c2 * 64 + c]);
    }
  }
}

// ---------------------------------------------------------------------------
// K2+K3: offset net + grid_sample + k/v convs, partitioned over px.
// grid: (8 px-chunks of 8, 16 bg), 512 thr (8 waves).
// ---------------------------------------------------------------------------
__global__ __launch_bounds__(512) void k_offset_sample(
    const float* __restrict__ q, const float* __restrict__ w1,
    const float* __restrict__ b1, const float* __restrict__ w2,
    const float* __restrict__ x, const float* __restrict__ kw,
    const float* __restrict__ vw, float* __restrict__ gkv,
    float* __restrict__ kh,
    unsigned short* __restrict__ vPh, unsigned short* __restrict__ vPl) {
  const int px0 = blockIdx.x << 3;   // 0,8,...,56
  const int bg  = blockIdx.y;
  const int g   = bg & 7;
  const int tid = threadIdx.x;
  __shared__ float ge[64 * 9];       // [c][lp] gelu outs, padded
  __shared__ float w1s[64 * 36];
  __shared__ float b1s[64];
  __shared__ float kws[64 * 33];
  __shared__ float vws[64 * 33];
  __shared__ float smp[32 * 9];      // [c][lj] sampled, padded
  __shared__ float xs_[8], ys_[8];

  for (int idx = tid; idx < 64 * 36; idx += 512) w1s[idx] = w1[idx];
  if (tid < 64) b1s[tid] = b1[tid];
  for (int idx = tid; idx < 2048; idx += 512) {
    int o = idx >> 5, c = idx & 31;
    kws[o * 33 + c] = kw[(g * 64 + o) * 32 + c];
    vws[o * 33 + c] = vw[(g * 64 + o) * 32 + c];
  }
  __syncthreads();

  // depthwise 6x6 s4 + bias + exact GELU: 64 c x 8 px, 1 per thread
  const float* qb = q + (size_t)bg * 64 * NPX;
  {
    int idx = tid;  // 0..511
    int c = idx >> 3, lp = idx & 7;
    int px = px0 + lp;
    int oy = px >> 3, ox = px & 7;
    const float* qc = qb + (size_t)c * NPX;
    float acc = 0.f;
#pragma unroll
    for (int ky = 0; ky < 6; ++ky) {
      int yy = oy * 4 - 1 + ky;
      if (yy < 0 || yy >= 32) continue;
#pragma unroll
      for (int kx = 0; kx < 6; ++kx) {
        int xx = ox * 4 - 1 + kx;
        if (xx < 0 || xx >= 32) continue;
        acc = fmaf(w1s[c * 36 + ky * 6 + kx], qc[yy * 32 + xx], acc);
      }
    }
    acc += b1s[c];
    ge[c * 9 + lp] = 0.5f * acc * (1.f + erff(acc * 0.70710678118654752440f));
  }
  __syncthreads();

  // 1x1 (64->2): 64 lanes per px, 1 channel each, shfl-reduce width 64
  {
    int lp = tid >> 6, sl = tid & 63;
    float gv = ge[sl * 9 + lp];
    float s0 = w2[sl] * gv;
    float s1 = w2[64 + sl] * gv;
#pragma unroll
    for (int off = 32; off > 0; off >>= 1) {
      s0 += __shfl_xor(s0, off, 64);
      s1 += __shfl_xor(s1, off, 64);
    }
    if (sl == 0) {
      float o0 = tanhf(s0) * 4.f;
      float o1 = tanhf(s1) * 4.f;
      int px = px0 + lp;
      int oy = px >> 3, ox = px & 7;
      float g0 = 2.f * ((float)ox + o0) / 7.f - 1.f;
      float g1 = 2.f * ((float)oy + o1) / 7.f - 1.f;
      gkv[(bg * 64 + px) * 2 + 0] = g0;
      gkv[(bg * 64 + px) * 2 + 1] = g1;
      xs_[lp] = (g0 + 1.f) * 16.f - 0.5f;
      ys_[lp] = (g1 + 1.f) * 16.f - 0.5f;
    }
  }
  __syncthreads();

  // bilinear sample: 32 c x 8 j (only tid<256 active)
  const float* imgb = x + (size_t)bg * 32 * NPX;
  if (tid < 256) {
    int c = tid >> 3, lj = tid & 7;
    float xx = xs_[lj], yy = ys_[lj];
    float x0f = floorf(xx), y0f = floorf(yy);
    int x0 = (int)x0f, y0 = (int)y0f;
    float wx1 = xx - x0f, wy1 = yy - y0f;
    float wx0 = 1.f - wx1, wy0 = 1.f - wy1;
    int x1 = x0 + 1, y1 = y0 + 1;
    bool vx0 = (x0 >= 0) & (x0 < 32), vx1 = (x1 >= 0) & (x1 < 32);
    bool vy0 = (y0 >= 0) & (y0 < 32), vy1 = (y1 >= 0) & (y1 < 32);
    int cx0 = min(max(x0, 0), 31), cx1 = min(max(x1, 0), 31);
    int cy0 = min(max(y0, 0), 31), cy1 = min(max(y1, 0), 31);
    const float* img = imgb + (size_t)c * NPX;
    float v00 = (vy0 && vx0) ? img[cy0 * 32 + cx0] : 0.f;
    float v01 = (vy0 && vx1) ? img[cy0 * 32 + cx1] : 0.f;
    float v10 = (vy1 && vx0) ? img[cy1 * 32 + cx0] : 0.f;
    float v11 = (vy1 && vx1) ? img[cy1 * 32 + cx1] : 0.f;
    smp[c * 9 + lj] = v00 * wy0 * wx0 + v01 * wy0 * wx1 +
                      v10 * wy1 * wx0 + v11 * wy1 * wx1;
  }
  __syncthreads();

  // k/v 1x1 convs: 8 j x 64 o, 1 per thread
  {
    int lj = tid >> 6, o = tid & 63;
    int j = px0 + lj;
    float ak0 = 0.f, ak1 = 0.f, av0 = 0.f, av1 = 0.f;
#pragma unroll
    for (int c = 0; c < 32; c += 2) {
      float s0 = smp[c * 9 + lj], s1 = smp[(c + 1) * 9 + lj];
      ak0 = fmaf(kws[o * 33 + c],     s0, ak0);
      ak1 = fmaf(kws[o * 33 + c + 1], s1, ak1);
      av0 = fmaf(vws[o * 33 + c],     s0, av0);
      av1 = fmaf(vws[o * 33 + c + 1], s1, av1);
    }
    kh[((size_t)bg * 64 + j) * 64 + o] = ak0 + ak1;
    // V -> bf16 hi/lo in MFMA B-fragment layout:
    float av = av0 + av1;
    unsigned short hi = f2bf(av);
    unsigned short lo = f2bf(av - bf2f(hi));
    int s  = (j >> 5) & 1, lgj = (j >> 3) & 3, r = j & 7;
    int nb = o >> 4, lmo = o & 15;
    size_t dst = (((size_t)(bg * 4 + nb) * 64) + lgj * 16 + lmo) * 16 + s * 8 + r;
    vPh[dst] = hi;
    vPl[dst] = lo;
  }
}

// ---------------------------------------------------------------------------
// K4: fused CPB-MLP + QK^T + softmax + PV, all MFMA (round-15 proven form).
// Only LDS is sim (4.2 KB); 2 barriers total.
// grid: (64 tiles, 16 bh), 256 thr = 4 waves; wave w owns j-cols [16w,16w+16)
// ---------------------------------------------------------------------------
__global__ __launch_bounds__(256) void k_attn(
    const float* __restrict__ qT, const float* __restrict__ kh,
    const unsigned short* __restrict__ vPh, const unsigned short* __restrict__ vPl,
    const float* __restrict__ gkv,
    const float* __restrict__ w1, const float* __restrict__ b1,
    const unsigned short* __restrict__ w2P, const float* __restrict__ b2,
    const float* __restrict__ w3, const float* __restrict__ b3,
    unsigned short* __restrict__ aoh, unsigned short* __restrict__ aol) {
  const int it  = blockIdx.x;     // 0..63
  const int bh  = blockIdx.y;     // 0..15
  const int i0  = it << 4;
  const int iy  = i0 >> 5;
  const int ixb = i0 & 31;
  const int tid = threadIdx.x;

  __shared__ float sim[16 * 65];

  const int w  = tid >> 6;   // wave 0..3
  const int l  = tid & 63;
  const int lm = l & 15;
  const int lg = l >> 4;
  const int jb = w * 16;
  const int j  = jb + lm;    // this thread's j-column for CPB/QK

  // --- W2 fragments: 8x coalesced 16B loads from packed global ---
  bf16x8 bw2[4][2];
  {
    const unsigned short* wp = w2P + (lg * 16 + lm) * 64;
#pragma unroll
    for (int c2t = 0; c2t < 4; ++c2t)
#pragma unroll
      for (int s = 0; s < 2; ++s)
        bw2[c2t][s] = *(const bf16x8*)(wp + (c2t * 2 + s) * 8);
  }
  // --- V B-fragments: 4 coalesced 16B loads from packed global ---
  bf16x8 bvh[2], bvl[2];
  {
    const size_t vbase = (((size_t)(bh * 4 + w) * 64) + l) * 16;
#pragma unroll
    for (int s = 0; s < 2; ++s) {
      bvh[s] = *(const bf16x8*)(vPh + vbase + s * 8);
      bvl[s] = *(const bf16x8*)(vPl + vbase + s * 8);
    }
  }

  // --- per-thread scalars (no LDS): k-grid coords + layer-1 hoists ---
  float kxv, vvj;
  {
    float2 kg = *(const float2*)(gkv + (bh * 64 + j) * 2);
    kxv = kg.x;
    float qyn = (2.f / 31.f) * (float)iy - 1.f;
    vvj = fast_slog1p(qyn - kg.y);
  }
  float w1v[16], tc[16];
#pragma unroll
  for (int s = 0; s < 2; ++s)
#pragma unroll
    for (int r = 0; r < 8; ++r) {
      int c = s * 32 + lg * 8 + r;
      float2 wv = *(const float2*)(w1 + c * 2);   // (w1x, w1y)
      w1v[s * 8 + r] = wv.x;
      tc[s * 8 + r]  = fmaf(wv.y, vvj, b1[c]);
    }
  // per-lane layer-3 constants: c2 = c2t*16 + lg*4 + r
  float b2r[4][4], w3r[4][4];
#pragma unroll
  for (int c2t = 0; c2t < 4; ++c2t)
#pragma unroll
    for (int r = 0; r < 4; ++r) {
      int c2 = c2t * 16 + lg * 4 + r;
      b2r[c2t][r] = b2[c2];
      w3r[c2t][r] = w3[c2];
    }
  const float b3v = b3[0];
  const float qxn0 = (2.f / 31.f) * (float)ixb - 1.f;

  // --- CPB pass: swapped operands; lane lm = point j-within-16; unroll 2 ---
#pragma unroll 2
  for (int il = 0; il < 16; ++il) {
    float qxn = fmaf((float)il, 2.f / 31.f, qxn0);
    float u = fast_slog1p(qxn - kxv);
    float h[16];
#pragma unroll
    for (int e = 0; e < 16; ++e)
      h[e] = fmaxf(fmaf(w1v[e], u, tc[e]), 0.f);
    bf16x8 hf[2];   // B-fragment: col=point=lm, k=c
#pragma unroll
    for (int s = 0; s < 2; ++s) {
      u32x4 wds;
#pragma unroll
      for (int p = 0; p < 4; ++p)
        wds[p] = cvt_pk(h[s * 8 + p * 2], h[s * 8 + p * 2 + 1]);
      hf[s] = __builtin_bit_cast(bf16x8, wds);
    }
    // D[m=c2][n=point]: lane holds point=lm, c2 = c2t*16 + lg*4 + r
    float tot = 0.f;
#pragma unroll
    for (int c2t = 0; c2t < 4; ++c2t) {
      f32x4 acc = (f32x4){b2r[c2t][0], b2r[c2t][1], b2r[c2t][2], b2r[c2t][3]};
      acc = __builtin_amdgcn_mfma_f32_16x16x32_bf16(bw2[c2t][0], hf[0], acc, 0, 0, 0);
      acc = __builtin_amdgcn_mfma_f32_16x16x32_bf16(bw2[c2t][1], hf[1], acc, 0, 0, 0);
#pragma unroll
      for (int r = 0; r < 4; ++r)
        tot = fmaf(fmaxf(acc[r], 0.f), w3r[c2t][r], tot);
    }
    tot += __shfl_xor(tot, 16);
    tot += __shfl_xor(tot, 32);
    if (lg == 0)
      sim[il * 65 + jb + lm] = tot + b3v;
  }

  // --- QK pass: same-wave stripe, ordered by per-wave DS ordering ---
  {
    bf16x8 aq[2], bk[2];
    const float* qb = qT + ((size_t)bh * NPX + i0 + lm) * 64;
    const float* kb = kh + ((size_t)(bh * 64 + j)) * 64;
#pragma unroll
    for (int s = 0; s < 2; ++s) {
      float4 q0 = *(const float4*)(qb + s * 32 + lg * 8);
      float4 q1 = *(const float4*)(qb + s * 32 + lg * 8 + 4);
      float4 k0 = *(const float4*)(kb + s * 32 + lg * 8);
      float4 k1 = *(const float4*)(kb + s * 32 + lg * 8 + 4);
      u32x4 wq, wk;
      wq[0] = cvt_pk(q0.x, q0.y); wq[1] = cvt_pk(q0.z, q0.w);
      wq[2] = cvt_pk(q1.x, q1.y); wq[3] = cvt_pk(q1.z, q1.w);
      wk[0] = cvt_pk(k0.x, k0.y); wk[1] = cvt_pk(k0.z, k0.w);
      wk[2] = cvt_pk(k1.x, k1.y); wk[3] = cvt_pk(k1.z, k1.w);
      aq[s] = __builtin_bit_cast(bf16x8, wq);
      bk[s] = __builtin_bit_cast(bf16x8, wk);
    }
    f32x4 qacc = (f32x4){0.f, 0.f, 0.f, 0.f};
    qacc = __builtin_amdgcn_mfma_f32_16x16x32_bf16(aq[0], bk[0], qacc, 0, 0, 0);
    qacc = __builtin_amdgcn_mfma_f32_16x16x32_bf16(aq[1], bk[1], qacc, 0, 0, 0);
#pragma unroll
    for (int r = 0; r < 4; ++r)
      sim[(lg * 4 + r) * 65 + jb + lm] += qacc[r];
  }
  __syncthreads();

  // --- softmax: 16 threads per row of 64 ---
  {
    int r = tid >> 4, sl = tid & 15;
    float sv[4];
    float m = -1e30f;
#pragma unroll
    for (int t = 0; t < 4; ++t) {
      sv[t] = sim[r * 65 + sl + (t << 4)];
      m = fmaxf(m, sv[t]);
    }
#pragma unroll
    for (int off = 8; off > 0; off >>= 1) m = fmaxf(m, __shfl_xor(m, off, 16));
    float ssum = 0.f;
#pragma unroll
    for (int t = 0; t < 4; ++t) { sv[t] = expf(sv[t] - m); ssum += sv[t]; }
#pragma unroll
    for (int off = 8; off > 0; off >>= 1) ssum += __shfl_xor(ssum, off, 16);
    float inv = 1.f / ssum;
#pragma unroll
    for (int t = 0; t < 4; ++t) sim[r * 65 + sl + (t << 4)] = sv[t] * inv;
  }
  __syncthreads();

  // --- PV via MFMA (P bf16 x V hi/lo), direct hi/lo epilogue ---
  {
    bf16x8 ap[2];
#pragma unroll
    for (int s = 0; s < 2; ++s) {
      u32x4 wp;
#pragma unroll
      for (int p = 0; p < 4; ++p)
        wp[p] = cvt_pk(sim[lm * 65 + s * 32 + lg * 8 + p * 2],
                       sim[lm * 65 + s * 32 + lg * 8 + p * 2 + 1]);
      ap[s] = __builtin_bit_cast(bf16x8, wp);
    }
    f32x4 po = (f32x4){0.f, 0.f, 0.f, 0.f};
    po = __builtin_amdgcn_mfma_f32_16x16x32_bf16(ap[0], bvh[0], po, 0, 0, 0);
    po = __builtin_amdgcn_mfma_f32_16x16x32_bf16(ap[1], bvh[1], po, 0, 0, 0);
    po = __builtin_amdgcn_mfma_f32_16x16x32_bf16(ap[0], bvl[0], po, 0, 0, 0);
    po = __builtin_amdgcn_mfma_f32_16x16x32_bf16(ap[1], bvl[1], po, 0, 0, 0);
    const int b = bh >> 3, h = bh & 7;
    size_t base = ((size_t)(b * 1024 + i0 + lg * 4)) * 512 + h * 64 + jb + lm;
#pragma unroll
    for (int r = 0; r < 4; ++r) {
      float v = po[r];
      unsigned short hi = f2bf(v);
      aoh[base + (size_t)r * 512] = hi;
      aol[base + (size_t)r * 512] = f2bf(v - bf2f(hi));
    }
  }
}

// ---------------------------------------------------------------------------
// K5: projection as split-bf16 MFMA GEMM (round-15 proven form)
// ---------------------------------------------------------------------------
__global__ __launch_bounds__(256) void k_proj_mfma(
    const unsigned short* __restrict__ aoh, const unsigned short* __restrict__ aol,
    const unsigned short* __restrict__ whP, const unsigned short* __restrict__ wlP,
    const float* __restrict__ ob, float* __restrict__ out) {
  const int p0 = blockIdx.x << 4;
  const int b  = p0 >> 10;
  const int pb = p0 & 1023;
  const int w  = threadIdx.x >> 6;
  const int l  = threadIdx.x & 63;
  const int lm = l & 15, lg = l >> 4;

  f32x4 acc[4];
#pragma unroll
  for (int nt = 0; nt < 4; ++nt) acc[nt] = (f32x4){0.f, 0.f, 0.f, 0.f};

  const unsigned short* arh = aoh + ((size_t)(p0 + lm)) * 512 + lg * 8;
  const unsigned short* arl = aol + ((size_t)(p0 + lm)) * 512 + lg * 8;
  const int ob0 = w * 64;

#pragma unroll 4
  for (int kt = 0; kt < 16; ++kt) {
    bf16x8 ah = *(const bf16x8*)(arh + kt * 32);
    bf16x8 al = *(const bf16x8*)(arl + kt * 32);
    const size_t wb = ((size_t)(kt * 4 + lg) * 256 + ob0 + lm) * 8;
#pragma unroll
    for (int nt = 0; nt < 4; ++nt) {
      bf16x8 bhf = *(const bf16x8*)(whP + wb + nt * 128);
      bf16x8 blf = *(const bf16x8*)(wlP + wb + nt * 128);
      acc[nt] = __builtin_amdgcn_mfma_f32_16x16x32_bf16(ah, bhf, acc[nt], 0, 0, 0);
      acc[nt] = __builtin_amdgcn_mfma_f32_16x16x32_bf16(ah, blf, acc[nt], 0, 0, 0);
      acc[nt] = __builtin_amdgcn_mfma_f32_16x16x32_bf16(al, bhf, acc[nt], 0, 0, 0);
    }
  }
#pragma unroll
  for (int nt = 0; nt < 4; ++nt) {
    int o = ob0 + nt * 16 + lm;
    float bias = ob[o];
    float4 v;
    v.x = acc[nt][0] + bias;
    v.y = acc[nt][1] + bias;
    v.z = acc[nt][2] + bias;
    v.w = acc[nt][3] + bias;
    *(float4*)(out + ((size_t)(b * 256 + o)) * NPX + pb + lg * 4) = v;
  }
}

// ---------------------------------------------------------------------------
extern "C" void kernel_launch(void* const* d_in, const int* in_sizes, int n_in,
                              void* d_out, int out_size, void* d_ws, size_t ws_size,
                              hipStream_t stream) {
  const float* x      = (const float*)d_in[0];
  const float* q_w    = (const float*)d_in[1];
  const float* k_w    = (const float*)d_in[2];
  const float* v_w    = (const float*)d_in[3];
  const float* out_w  = (const float*)d_in[4];
  const float* out_b  = (const float*)d_in[5];
  const float* off_w1 = (const float*)d_in[6];
  const float* off_b1 = (const float*)d_in[7];
  const float* off_w2 = (const float*)d_in[8];
  const float* cpb_w1 = (const float*)d_in[9];
  const float* cpb_b1 = (const float*)d_in[10];
  const float* cpb_w2 = (const float*)d_in[11];
  const float* cpb_b2 = (const float*)d_in[12];
  const float* cpb_w3 = (const float*)d_in[13];
  const float* cpb_b3 = (const float*)d_in[14];
  float* out = (float*)d_out;

  float* ws  = (float*)d_ws;
  float* q   = ws;                          // 1048576 f; reused as aoh/aol
  unsigned short* aoh = (unsigned short*)q; // 2048*512 shorts
  unsigned short* aol = aoh + 2048 * 512;   // 2048*512 shorts
  float* qT  = ws + 1048576;                // 1048576 f
  float* kh  = qT + 1048576;                // 65536 f
  float* gkv = kh + 65536;                  // 2048 f
  unsigned short* whP = (unsigned short*)(gkv + 2048);  // 131072 shorts
  unsigned short* wlP = whP + 131072;                   // 131072 shorts
  unsigned short* w2P = wlP + 131072;                   // 4096 shorts
  unsigned short* vPh = w2P + 4096;                     // 65536 shorts
  unsigned short* vPl = vPh + 65536;                    // 65536 shorts

  k_pre<<<1025, 256, 0, stream>>>(x, q_w, out_w, cpb_w2, q, qT, whP, wlP, w2P);
  k_offset_sample<<<dim3(8, 16), 512, 0, stream>>>(q, off_w1, off_b1, off_w2,
                                                   x, k_w, v_w, gkv, kh, vPh, vPl);
  k_attn<<<dim3(64, 16), 256, 0, stream>>>(qT, kh, vPh, vPl, gkv, cpb_w1, cpb_b1,
                                           w2P, cpb_b2, cpb_w3, cpb_b3,
                                           aoh, aol);
  k_proj_mfma<<<128, 256, 0, stream>>>(aoh, aol, whP, wlP, out_b, out);
}